// Round 8
// baseline (231.343 us; speedup 1.0000x reference)
//
#include <hip/hip_runtime.h>
#include <math.h>

// Problem constants (fixed by the reference)
#define NHEADS 8
#define HDIM   128
#define WIN    16
#define DIM    1024
#define QKVDIM 3072
#define SEQ    2048
#define BATCH  4
#define MROWS  (BATCH * SEQ)   // 8192
#define RMS_EPS 1e-6f

typedef __bf16 bf16x8 __attribute__((ext_vector_type(8)));
typedef unsigned short u16x8 __attribute__((ext_vector_type(8)));
typedef float  f32x4  __attribute__((ext_vector_type(4)));

// ---------------- bf16 bit helpers (RNE) ----------------
__device__ __forceinline__ unsigned short f2b(float f) {
    union { float f; unsigned u; } c; c.f = f;
    return (unsigned short)((c.u + 0x7FFFu + ((c.u >> 16) & 1u)) >> 16);
}
__device__ __forceinline__ float b2f(unsigned short u) {
    union { unsigned u; float f; } c; c.u = ((unsigned)u) << 16; return c.f;
}
__device__ __forceinline__ bf16x8 u2b(u16x8 u) {
    union { u16x8 u; bf16x8 b; } c; c.u = u; return c.b;
}

__device__ __forceinline__ void storec(unsigned short* p, float v) { *p = f2b(v); }
__device__ __forceinline__ void storec(float* p, float v) { *p = v; }

// ---------------- fused cast: x + 4 weights ----------------
// blocks 0..8191: x -> xb. 8192..12287: weights -> wb (contiguous wq|wk|wv|wo)
__global__ __launch_bounds__(256) void cast_all(const float* __restrict__ x,
                                                const float* __restrict__ w0,
                                                const float* __restrict__ w1,
                                                const float* __restrict__ w2,
                                                const float* __restrict__ w3,
                                                unsigned short* __restrict__ xb,
                                                unsigned short* __restrict__ wb)
{
    const int b = blockIdx.x;
    const int t = threadIdx.x;
    const float* src;
    unsigned short* dst;
    int i;
    if (b < 8192) {
        i = b * 256 + t;
        src = x; dst = xb;
    } else {
        const int bb = b - 8192;
        const int which = bb >> 10;
        i = (bb & 1023) * 256 + t;
        src = which == 0 ? w0 : which == 1 ? w1 : which == 2 ? w2 : w3;
        dst = wb + (size_t)which * DIM * DIM;
    }
    const float4 v = ((const float4*)src)[i];
    ushort4 o;
    o.x = f2b(v.x); o.y = f2b(v.y); o.z = f2b(v.z); o.w = f2b(v.w);
    ((ushort4*)dst)[i] = o;
}

// ---------------- MFMA GEMM (NT): C[M,N] = A[M,K] * B[N,K]^T, bf16 in, fp32 acc ----------------
// r4-exact inner structure: 128x128 tile, BK=32, identity chunk map.
// If partial != nullptr: for q/k column blocks (bn0 < 2048), each wave stores its
// 64-col per-row sum-of-squares partial to partial[which][row][slot] with a PLAIN
// store (slot = ((bn0>>6)&15)+wn). No atomics: r5-r7 showed the atomicAdd epilogue
// cost ~12 us/dispatch (WRITE_SIZE +8MB of RMW traffic, QKV 77.5->90 us).
template <typename TC>
__global__ __launch_bounds__(256) void gemm_nt_mfma(const unsigned short* __restrict__ A,
                                                    const unsigned short* __restrict__ B,
                                                    TC* __restrict__ C,
                                                    float* __restrict__ partial,
                                                    int M, int N, int K)
{
    __shared__ __align__(16) __bf16 As[128 * 32];
    __shared__ __align__(16) __bf16 Bs[128 * 32];

    const int t    = threadIdx.x;
    const int w    = t >> 6;
    const int lane = t & 63;
    const int wm   = w >> 1;
    const int wn   = w & 1;
    const int bm0  = blockIdx.y * 128;
    const int bn0  = blockIdx.x * 128;

    // staging: wave w covers row-segments {w, w+4} (16 rows each).
    // lane l -> row l>>2, chunk l&3 (contiguous 64B per 4-lane cluster)
    const int sr = lane >> 2;
    const int kc = (lane & 3) * 8;

    const unsigned short* gA0 = A + (size_t)(bm0 + w * 16 + sr) * K + kc;
    const unsigned short* gA1 = gA0 + (size_t)64 * K;
    const unsigned short* gB0 = B + (size_t)(bn0 + w * 16 + sr) * K + kc;
    const unsigned short* gB1 = gB0 + (size_t)64 * K;

    __bf16* lA0 = &As[(w * 16) * 32];
    __bf16* lA1 = &As[(w * 16 + 64) * 32];
    __bf16* lB0 = &Bs[(w * 16) * 32];
    __bf16* lB1 = &Bs[(w * 16 + 64) * 32];

    const int frow = lane & 15;
    const int quad = lane >> 4;
    const int fk   = quad * 8;

    f32x4 acc[4][4];
    #pragma unroll
    for (int i = 0; i < 4; ++i)
        #pragma unroll
        for (int j = 0; j < 4; ++j)
            #pragma unroll
            for (int e = 0; e < 4; ++e) acc[i][j][e] = 0.f;

    for (int kt = 0; kt < K; kt += 32) {
        __syncthreads();   // previous iteration's ds_reads retired before overwrite
        __builtin_amdgcn_global_load_lds((const __attribute__((address_space(1))) void*)(gA0 + kt),
                                         (__attribute__((address_space(3))) void*)lA0, 16, 0, 0);
        __builtin_amdgcn_global_load_lds((const __attribute__((address_space(1))) void*)(gA1 + kt),
                                         (__attribute__((address_space(3))) void*)lA1, 16, 0, 0);
        __builtin_amdgcn_global_load_lds((const __attribute__((address_space(1))) void*)(gB0 + kt),
                                         (__attribute__((address_space(3))) void*)lB0, 16, 0, 0);
        __builtin_amdgcn_global_load_lds((const __attribute__((address_space(1))) void*)(gB1 + kt),
                                         (__attribute__((address_space(3))) void*)lB1, 16, 0, 0);
        __syncthreads();   // tile resident

        bf16x8 af[4], bg[4];
        #pragma unroll
        for (int i = 0; i < 4; ++i) {
            af[i] = *(const bf16x8*)&As[(wm * 64 + i * 16 + frow) * 32 + fk];
            bg[i] = *(const bf16x8*)&Bs[(wn * 64 + i * 16 + frow) * 32 + fk];
        }
        #pragma unroll
        for (int i = 0; i < 4; ++i)
            #pragma unroll
            for (int j = 0; j < 4; ++j)
                acc[i][j] = __builtin_amdgcn_mfma_f32_16x16x32_bf16(af[i], bg[j], acc[i][j], 0, 0, 0);
    }

    // epilogue: C/D layout col=lane&15, row=(lane>>4)*4+reg
    const int m_base = bm0 + wm * 64;
    const int n_base = bn0 + wn * 64;
    const int col    = frow;
    const int rquad  = quad * 4;
    #pragma unroll
    for (int i = 0; i < 4; ++i)
        #pragma unroll
        for (int r = 0; r < 4; ++r) {
            TC* crow = C + (size_t)(m_base + i * 16 + rquad + r) * N + n_base + col;
            #pragma unroll
            for (int j = 0; j < 4; ++j)
                storec(crow + j * 16, acc[i][j][r]);
        }

    if (partial != nullptr && bn0 < 2 * DIM) {
        const int which = bn0 >> 10;                 // 0 = q cols, 1 = k cols
        const int slot  = ((bn0 >> 6) & 15) + wn;    // 16 col-halves per DIM
        float* pp = partial + (size_t)which * MROWS * 16;
        #pragma unroll
        for (int i = 0; i < 4; ++i)
            #pragma unroll
            for (int r = 0; r < 4; ++r) {
                float p = acc[i][0][r] * acc[i][0][r] + acc[i][1][r] * acc[i][1][r]
                        + acc[i][2][r] * acc[i][2][r] + acc[i][3][r] * acc[i][3][r];
                p += __shfl_xor(p, 1, 64);
                p += __shfl_xor(p, 2, 64);
                p += __shfl_xor(p, 4, 64);
                p += __shfl_xor(p, 8, 64);
                if (frow == 0)
                    pp[(size_t)(m_base + i * 16 + rquad + r) * 16 + slot] = p;
            }
    }
}

// ---------------- MFMA sliding-window attention, RMSNorm fused on load ----------------
// grid (MROWS/64, NHEADS). Block: 64 queries x 1 head, 4 waves x 16 queries.
// Preamble reduces 16 sumsq partials per needed row into LDS inv-scale tables,
// then Q/K are normalized on the fly: val * inv * w[col].
__global__ __launch_bounds__(256) void attn_mfma(const unsigned short* __restrict__ qkv,
                                                 const float* __restrict__ partial,
                                                 const float* __restrict__ qw,
                                                 const float* __restrict__ kw,
                                                 unsigned short* __restrict__ o)
{
    __shared__ __align__(16) unsigned short Klds[80 * 136];
    __shared__ __align__(16) unsigned short Vt[128 * 88];
    __shared__ __align__(16) unsigned short Plds[4 * 16 * 40];
    __shared__ float qinv_s[64];
    __shared__ float kinv_s[80];

    const int t  = threadIdx.x;
    const int qb = blockIdx.x;
    const int h  = blockIdx.y;
    const int r0 = qb * 64;             // first query's global row
    const int i0 = r0 & (SEQ - 1);      // seq-local (block never spans batches)
    const int bb = r0 - i0;             // batch base row

    // ---- preamble: reduce sumsq partials -> inv scales in LDS
    if (t < 144) {
        int row;
        const float* pp;
        if (t < 64) { row = r0 + t; pp = partial; }
        else {
            const int lr = t - 64;
            const int ks = i0 - 16 + lr;
            row = bb + (ks < 0 ? 0 : ks);
            pp = partial + (size_t)MROWS * 16;
        }
        const float4* p4 = (const float4*)(pp + (size_t)row * 16);
        const float4 a = p4[0], b = p4[1], c = p4[2], d = p4[3];
        const float s = (a.x + a.y + a.z + a.w) + (b.x + b.y + b.z + b.w)
                      + (c.x + c.y + c.z + c.w) + (d.x + d.y + d.z + d.w);
        const float iv = rsqrtf(s * (1.0f / DIM) + RMS_EPS);
        if (t < 64) qinv_s[t] = iv; else kinv_s[t - 64] = iv;
    }
    __syncthreads();

    const unsigned short* kg = qkv + DIM + h * HDIM;
    const unsigned short* vg = qkv + 2 * DIM + h * HDIM;

    #pragma unroll
    for (int it = 0; it < 5; ++it) {
        const int c = it * 256 + t;
        {   // K: row-major chunk map; normalize while staging
            const int lr = c >> 4, c8 = c & 15;
            const int ks = i0 - 16 + lr;
            const int rc = ks < 0 ? 0 : ks;          // clamped rows masked later
            const float ksc = kinv_s[lr];
            const u16x8 kv = *(const u16x8*)(kg + (size_t)(bb + rc) * QKVDIM + c8 * 8);
            u16x8 ko;
            #pragma unroll
            for (int e = 0; e < 8; ++e)
                ko[e] = f2b(b2f(kv[e]) * ksc * kw[h * HDIM + c8 * 8 + e]);
            *(u16x8*)&Klds[lr * 136 + c8 * 8] = ko;
        }
        {   // V: key-consecutive chunk map -> transposed scatter (no norm)
            const int c8 = c / 80, lr = c - c8 * 80;
            const int ks = i0 - 16 + lr;
            const int rc = ks < 0 ? 0 : ks;
            const u16x8 vv = *(const u16x8*)(vg + (size_t)(bb + rc) * QKVDIM + c8 * 8);
            #pragma unroll
            for (int e = 0; e < 8; ++e)
                Vt[(c8 * 8 + e) * 88 + lr] = vv[e];
        }
    }
    __syncthreads();

    const int w    = t >> 6;
    const int lane = t & 63;
    const int frow = lane & 15;
    const int quad = lane >> 4;
    const int fk   = quad * 8;

    // ---- S = Q K^T; Q normalized on load
    f32x4 s0 = {0.f, 0.f, 0.f, 0.f}, s1 = {0.f, 0.f, 0.f, 0.f};
    const unsigned short* qg = qkv + h * HDIM;
    const size_t qrow = (size_t)(r0 + w * 16 + frow) * QKVDIM;
    const float qsc = qinv_s[w * 16 + frow];
    #pragma unroll
    for (int kt = 0; kt < 4; ++kt) {
        const u16x8 qa = *(const u16x8*)(qg + qrow + kt * 32 + fk);
        u16x8 qn;
        #pragma unroll
        for (int e = 0; e < 8; ++e)
            qn[e] = f2b(b2f(qa[e]) * qsc * qw[h * HDIM + kt * 32 + fk + e]);
        const bf16x8 af = u2b(qn);
        const bf16x8 b0 = *(const bf16x8*)&Klds[(w * 16 + frow) * 136 + kt * 32 + fk];
        const bf16x8 b1 = *(const bf16x8*)&Klds[(w * 16 + 16 + frow) * 136 + kt * 32 + fk];
        s0 = __builtin_amdgcn_mfma_f32_16x16x32_bf16(af, b0, s0, 0, 0, 0);
        s1 = __builtin_amdgcn_mfma_f32_16x16x32_bf16(af, b1, s1, 0, 0, 0);
    }

    // ---- bias + mask + softmax (C-layout: rows m=quad*4+r, col=frow)
    const float scl   = 0.088388347648318447f;   // 1/sqrt(128)
    const float slope = exp2f(-(float)(h + 1));
    const bool  lead  = (i0 == 0) && (w == 0);
    const int   col   = frow;
    float inv[4];
    #pragma unroll
    for (int r = 0; r < 4; ++r) {
        const int m = quad * 4 + r;
        float v0 = (col < m || lead) ? -1e30f : s0[r] * scl + slope * (float)(col - 16 - m);
        float v1 = (col > m)         ? -1e30f : s1[r] * scl + slope * (float)(col - m);
        float mx = fmaxf(v0, v1);
        #pragma unroll
        for (int off = 1; off < 16; off <<= 1) mx = fmaxf(mx, __shfl_xor(mx, off, 64));
        const float e0 = __expf(v0 - mx);
        const float e1 = __expf(v1 - mx);
        float sm = e0 + e1;
        #pragma unroll
        for (int off = 1; off < 16; off <<= 1) sm += __shfl_xor(sm, off, 64);
        inv[r] = 1.0f / sm;
        Plds[(w * 16 + m) * 40 + col]      = f2b(e0);
        Plds[(w * 16 + m) * 40 + 16 + col] = f2b(e1);
    }

    // ---- O = P V
    const bf16x8 pf = *(const bf16x8*)&Plds[(w * 16 + frow) * 40 + fk];
    f32x4 oa[8];
    #pragma unroll
    for (int nt = 0; nt < 8; ++nt) {
        oa[nt][0] = 0.f; oa[nt][1] = 0.f; oa[nt][2] = 0.f; oa[nt][3] = 0.f;
        const bf16x8 vf = *(const bf16x8*)&Vt[(nt * 16 + frow) * 88 + w * 16 + fk];
        oa[nt] = __builtin_amdgcn_mfma_f32_16x16x32_bf16(pf, vf, oa[nt], 0, 0, 0);
    }

    #pragma unroll
    for (int nt = 0; nt < 8; ++nt)
        #pragma unroll
        for (int r = 0; r < 4; ++r) {
            const int m = quad * 4 + r;
            o[(size_t)(r0 + w * 16 + m) * DIM + h * HDIM + nt * 16 + col] =
                f2b(oa[nt][r] * inv[r]);
        }
}

// ---------------- launch ----------------
extern "C" void kernel_launch(void* const* d_in, const int* in_sizes, int n_in,
                              void* d_out, int out_size, void* d_ws, size_t ws_size,
                              hipStream_t stream)
{
    const float* x  = (const float*)d_in[0];
    const float* wq = (const float*)d_in[1];
    const float* wk = (const float*)d_in[2];
    const float* wv = (const float*)d_in[3];
    const float* wo = (const float*)d_in[4];
    const float* wo_ = wo; (void)wo_;
    const float* qw = (const float*)d_in[5];
    const float* kw = (const float*)d_in[6];
    float* out = (float*)d_out;

    // ws: xb 16MB | weights 8MB | xqkv 48MB | ob 16MB | partials 1MB  (~89MB)
    unsigned short* xb   = (unsigned short*)d_ws;
    unsigned short* wb   = xb + (size_t)MROWS * DIM;              // wq|wk|wv|wo
    unsigned short* xqkv = wb + (size_t)4 * DIM * DIM;
    unsigned short* ob   = xqkv + (size_t)MROWS * QKVDIM;
    float*          pss  = (float*)(ob + (size_t)MROWS * DIM);    // [2][MROWS][16]
    unsigned short* wob  = wb + (size_t)3 * DIM * DIM;

    cast_all<<<12288, 256, 0, stream>>>(x, wq, wk, wv, wo, xb, wb);

    gemm_nt_mfma<unsigned short><<<dim3(QKVDIM / 128, MROWS / 128), 256, 0, stream>>>(
        xb, wb, xqkv, pss, MROWS, QKVDIM, DIM);

    attn_mfma<<<dim3(MROWS / 64, NHEADS), 256, 0, stream>>>(xqkv, pss, qw, kw, ob);

    gemm_nt_mfma<float><<<dim3(DIM / 128, MROWS / 128), 256, 0, stream>>>(
        ob, wob, out, nullptr, MROWS, DIM, DIM);
}

// Round 9
// 224.689 us; speedup vs baseline: 1.0296x; 1.0296x over previous
//
#include <hip/hip_runtime.h>
#include <math.h>

// Problem constants (fixed by the reference)
#define NHEADS 8
#define HDIM   128
#define WIN    16
#define DIM    1024
#define QKVDIM 3072
#define SEQ    2048
#define BATCH  4
#define MROWS  (BATCH * SEQ)   // 8192
#define RMS_EPS 1e-6f

typedef __bf16 bf16x8 __attribute__((ext_vector_type(8)));
typedef unsigned short u16x8 __attribute__((ext_vector_type(8)));
typedef float  f32x4  __attribute__((ext_vector_type(4)));

// ---------------- bf16 bit helpers (RNE) ----------------
__device__ __forceinline__ unsigned short f2b(float f) {
    union { float f; unsigned u; } c; c.f = f;
    return (unsigned short)((c.u + 0x7FFFu + ((c.u >> 16) & 1u)) >> 16);
}
__device__ __forceinline__ float b2f(unsigned short u) {
    union { unsigned u; float f; } c; c.u = ((unsigned)u) << 16; return c.f;
}
__device__ __forceinline__ bf16x8 u2b(u16x8 u) {
    union { u16x8 u; bf16x8 b; } c; c.u = u; return c.b;
}

__device__ __forceinline__ void storec(unsigned short* p, float v) { *p = f2b(v); }
__device__ __forceinline__ void storec(float* p, float v) { *p = v; }

// ---------------- fused cast: x + 4 weights ----------------
// blocks 0..8191: x -> xb. 8192..12287: weights -> wb (contiguous wq|wk|wv|wo)
__global__ __launch_bounds__(256) void cast_all(const float* __restrict__ x,
                                                const float* __restrict__ w0,
                                                const float* __restrict__ w1,
                                                const float* __restrict__ w2,
                                                const float* __restrict__ w3,
                                                unsigned short* __restrict__ xb,
                                                unsigned short* __restrict__ wb)
{
    const int b = blockIdx.x;
    const int t = threadIdx.x;
    const float* src;
    unsigned short* dst;
    int i;
    if (b < 8192) {
        i = b * 256 + t;
        src = x; dst = xb;
    } else {
        const int bb = b - 8192;
        const int which = bb >> 10;
        i = (bb & 1023) * 256 + t;
        src = which == 0 ? w0 : which == 1 ? w1 : which == 2 ? w2 : w3;
        dst = wb + (size_t)which * DIM * DIM;
    }
    const float4 v = ((const float4*)src)[i];
    ushort4 o;
    o.x = f2b(v.x); o.y = f2b(v.y); o.z = f2b(v.z); o.w = f2b(v.w);
    ((ushort4*)dst)[i] = o;
}

// ---------------- MFMA GEMM (NT): C[M,N] = A[M,K] * B[N,K]^T, bf16 in, fp32 acc ----------------
// r4-EXACT kernel (77.5 us QKV, MfmaUtil 28.4%): 128x128 tile, BK=32, identity chunk
// map. NO extra epilogue code: r5-r8 proved ANY sumsq epilogue variant (atomic or
// plain-store) perturbs K-loop codegen and costs ~12 us/dispatch (+24% VALU cycles).
template <typename TC>
__global__ __launch_bounds__(256) void gemm_nt_mfma(const unsigned short* __restrict__ A,
                                                    const unsigned short* __restrict__ B,
                                                    TC* __restrict__ C,
                                                    int M, int N, int K)
{
    __shared__ __align__(16) __bf16 As[128 * 32];
    __shared__ __align__(16) __bf16 Bs[128 * 32];

    const int t    = threadIdx.x;
    const int w    = t >> 6;
    const int lane = t & 63;
    const int wm   = w >> 1;
    const int wn   = w & 1;
    const int bm0  = blockIdx.y * 128;
    const int bn0  = blockIdx.x * 128;

    // staging: wave w covers row-segments {w, w+4} (16 rows each).
    // lane l -> row l>>2, chunk l&3 (contiguous 64B per 4-lane cluster)
    const int sr = lane >> 2;
    const int kc = (lane & 3) * 8;

    const unsigned short* gA0 = A + (size_t)(bm0 + w * 16 + sr) * K + kc;
    const unsigned short* gA1 = gA0 + (size_t)64 * K;
    const unsigned short* gB0 = B + (size_t)(bn0 + w * 16 + sr) * K + kc;
    const unsigned short* gB1 = gB0 + (size_t)64 * K;

    __bf16* lA0 = &As[(w * 16) * 32];
    __bf16* lA1 = &As[(w * 16 + 64) * 32];
    __bf16* lB0 = &Bs[(w * 16) * 32];
    __bf16* lB1 = &Bs[(w * 16 + 64) * 32];

    const int frow = lane & 15;
    const int quad = lane >> 4;
    const int fk   = quad * 8;

    f32x4 acc[4][4];
    #pragma unroll
    for (int i = 0; i < 4; ++i)
        #pragma unroll
        for (int j = 0; j < 4; ++j)
            #pragma unroll
            for (int e = 0; e < 4; ++e) acc[i][j][e] = 0.f;

    for (int kt = 0; kt < K; kt += 32) {
        __syncthreads();   // previous iteration's ds_reads retired before overwrite
        __builtin_amdgcn_global_load_lds((const __attribute__((address_space(1))) void*)(gA0 + kt),
                                         (__attribute__((address_space(3))) void*)lA0, 16, 0, 0);
        __builtin_amdgcn_global_load_lds((const __attribute__((address_space(1))) void*)(gA1 + kt),
                                         (__attribute__((address_space(3))) void*)lA1, 16, 0, 0);
        __builtin_amdgcn_global_load_lds((const __attribute__((address_space(1))) void*)(gB0 + kt),
                                         (__attribute__((address_space(3))) void*)lB0, 16, 0, 0);
        __builtin_amdgcn_global_load_lds((const __attribute__((address_space(1))) void*)(gB1 + kt),
                                         (__attribute__((address_space(3))) void*)lB1, 16, 0, 0);
        __syncthreads();   // tile resident

        bf16x8 af[4], bg[4];
        #pragma unroll
        for (int i = 0; i < 4; ++i) {
            af[i] = *(const bf16x8*)&As[(wm * 64 + i * 16 + frow) * 32 + fk];
            bg[i] = *(const bf16x8*)&Bs[(wn * 64 + i * 16 + frow) * 32 + fk];
        }
        #pragma unroll
        for (int i = 0; i < 4; ++i)
            #pragma unroll
            for (int j = 0; j < 4; ++j)
                acc[i][j] = __builtin_amdgcn_mfma_f32_16x16x32_bf16(af[i], bg[j], acc[i][j], 0, 0, 0);
    }

    // epilogue: C/D layout col=lane&15, row=(lane>>4)*4+reg
    const int m_base = bm0 + wm * 64;
    const int n_base = bn0 + wn * 64;
    const int col    = frow;
    const int rquad  = quad * 4;
    #pragma unroll
    for (int i = 0; i < 4; ++i)
        #pragma unroll
        for (int r = 0; r < 4; ++r) {
            TC* crow = C + (size_t)(m_base + i * 16 + rquad + r) * N + n_base + col;
            #pragma unroll
            for (int j = 0; j < 4; ++j)
                storec(crow + j * 16, acc[i][j][r]);
        }
}

// ---------------- inverse-RMS scales from xqkv ----------------
// one block per row: threads 0..127 sum q cols (0..1023), 128..255 sum k cols
// (1024..2047); two wave-reduces + LDS combine; writes inv[0][row] (q) and
// inv[1][row] (k). 32 MB read, memory-bound (~8 us).
__global__ __launch_bounds__(256) void rms_inv(const unsigned short* __restrict__ xqkv,
                                               float* __restrict__ inv)
{
    const int row  = blockIdx.x;
    const int t    = threadIdx.x;
    const int lane = t & 63;
    const int wv   = t >> 6;           // waves 0,1 -> q; 2,3 -> k
    const int part = t >> 7;           // 0 = q, 1 = k

    const u16x8 u = *(const u16x8*)(xqkv + (size_t)row * QKVDIM + part * DIM + (t & 127) * 8);
    float s = 0.f;
    #pragma unroll
    for (int e = 0; e < 8; ++e) { const float f = b2f(u[e]); s += f * f; }
    #pragma unroll
    for (int off = 32; off > 0; off >>= 1) s += __shfl_xor(s, off, 64);

    __shared__ float red[4];
    if (lane == 0) red[wv] = s;
    __syncthreads();
    if (t == 0) inv[row]         = rsqrtf((red[0] + red[1]) * (1.0f / DIM) + RMS_EPS);
    if (t == 1) inv[MROWS + row] = rsqrtf((red[2] + red[3]) * (1.0f / DIM) + RMS_EPS);
}

// ---------------- MFMA sliding-window attention, RMSNorm fused on load ----------------
// grid (MROWS/64, NHEADS). Block: 64 queries x 1 head, 4 waves x 16 queries.
// Preamble loads precomputed inv scales into LDS; Q/K normalized on the fly.
__global__ __launch_bounds__(256) void attn_mfma(const unsigned short* __restrict__ qkv,
                                                 const float* __restrict__ inv_g,
                                                 const float* __restrict__ qw,
                                                 const float* __restrict__ kw,
                                                 unsigned short* __restrict__ o)
{
    __shared__ __align__(16) unsigned short Klds[80 * 136];
    __shared__ __align__(16) unsigned short Vt[128 * 88];
    __shared__ __align__(16) unsigned short Plds[4 * 16 * 40];
    __shared__ float qinv_s[64];
    __shared__ float kinv_s[80];

    const int t  = threadIdx.x;
    const int qb = blockIdx.x;
    const int h  = blockIdx.y;
    const int r0 = qb * 64;             // first query's global row
    const int i0 = r0 & (SEQ - 1);      // seq-local (block never spans batches)
    const int bb = r0 - i0;             // batch base row

    // ---- preamble: inv-scale table lookups
    if (t < 144) {
        if (t < 64) qinv_s[t] = inv_g[r0 + t];
        else {
            const int lr = t - 64;
            const int ks = i0 - 16 + lr;
            kinv_s[lr] = inv_g[MROWS + bb + (ks < 0 ? 0 : ks)];
        }
    }
    __syncthreads();

    const unsigned short* kg = qkv + DIM + h * HDIM;
    const unsigned short* vg = qkv + 2 * DIM + h * HDIM;

    #pragma unroll
    for (int it = 0; it < 5; ++it) {
        const int c = it * 256 + t;
        {   // K: row-major chunk map; normalize while staging
            const int lr = c >> 4, c8 = c & 15;
            const int ks = i0 - 16 + lr;
            const int rc = ks < 0 ? 0 : ks;          // clamped rows masked later
            const float ksc = kinv_s[lr];
            const u16x8 kv = *(const u16x8*)(kg + (size_t)(bb + rc) * QKVDIM + c8 * 8);
            u16x8 ko;
            #pragma unroll
            for (int e = 0; e < 8; ++e)
                ko[e] = f2b(b2f(kv[e]) * ksc * kw[h * HDIM + c8 * 8 + e]);
            *(u16x8*)&Klds[lr * 136 + c8 * 8] = ko;
        }
        {   // V: key-consecutive chunk map -> transposed scatter (no norm)
            const int c8 = c / 80, lr = c - c8 * 80;
            const int ks = i0 - 16 + lr;
            const int rc = ks < 0 ? 0 : ks;
            const u16x8 vv = *(const u16x8*)(vg + (size_t)(bb + rc) * QKVDIM + c8 * 8);
            #pragma unroll
            for (int e = 0; e < 8; ++e)
                Vt[(c8 * 8 + e) * 88 + lr] = vv[e];
        }
    }
    __syncthreads();

    const int w    = t >> 6;
    const int lane = t & 63;
    const int frow = lane & 15;
    const int quad = lane >> 4;
    const int fk   = quad * 8;

    // ---- S = Q K^T; Q normalized on load
    f32x4 s0 = {0.f, 0.f, 0.f, 0.f}, s1 = {0.f, 0.f, 0.f, 0.f};
    const unsigned short* qg = qkv + h * HDIM;
    const size_t qrow = (size_t)(r0 + w * 16 + frow) * QKVDIM;
    const float qsc = qinv_s[w * 16 + frow];
    #pragma unroll
    for (int kt = 0; kt < 4; ++kt) {
        const u16x8 qa = *(const u16x8*)(qg + qrow + kt * 32 + fk);
        u16x8 qn;
        #pragma unroll
        for (int e = 0; e < 8; ++e)
            qn[e] = f2b(b2f(qa[e]) * qsc * qw[h * HDIM + kt * 32 + fk + e]);
        const bf16x8 af = u2b(qn);
        const bf16x8 b0 = *(const bf16x8*)&Klds[(w * 16 + frow) * 136 + kt * 32 + fk];
        const bf16x8 b1 = *(const bf16x8*)&Klds[(w * 16 + 16 + frow) * 136 + kt * 32 + fk];
        s0 = __builtin_amdgcn_mfma_f32_16x16x32_bf16(af, b0, s0, 0, 0, 0);
        s1 = __builtin_amdgcn_mfma_f32_16x16x32_bf16(af, b1, s1, 0, 0, 0);
    }

    // ---- bias + mask + softmax (C-layout: rows m=quad*4+r, col=frow)
    const float scl   = 0.088388347648318447f;   // 1/sqrt(128)
    const float slope = exp2f(-(float)(h + 1));
    const bool  lead  = (i0 == 0) && (w == 0);
    const int   col   = frow;
    float inv[4];
    #pragma unroll
    for (int r = 0; r < 4; ++r) {
        const int m = quad * 4 + r;
        float v0 = (col < m || lead) ? -1e30f : s0[r] * scl + slope * (float)(col - 16 - m);
        float v1 = (col > m)         ? -1e30f : s1[r] * scl + slope * (float)(col - m);
        float mx = fmaxf(v0, v1);
        #pragma unroll
        for (int off = 1; off < 16; off <<= 1) mx = fmaxf(mx, __shfl_xor(mx, off, 64));
        const float e0 = __expf(v0 - mx);
        const float e1 = __expf(v1 - mx);
        float sm = e0 + e1;
        #pragma unroll
        for (int off = 1; off < 16; off <<= 1) sm += __shfl_xor(sm, off, 64);
        inv[r] = 1.0f / sm;
        Plds[(w * 16 + m) * 40 + col]      = f2b(e0);
        Plds[(w * 16 + m) * 40 + 16 + col] = f2b(e1);
    }

    // ---- O = P V
    const bf16x8 pf = *(const bf16x8*)&Plds[(w * 16 + frow) * 40 + fk];
    f32x4 oa[8];
    #pragma unroll
    for (int nt = 0; nt < 8; ++nt) {
        oa[nt][0] = 0.f; oa[nt][1] = 0.f; oa[nt][2] = 0.f; oa[nt][3] = 0.f;
        const bf16x8 vf = *(const bf16x8*)&Vt[(nt * 16 + frow) * 88 + w * 16 + fk];
        oa[nt] = __builtin_amdgcn_mfma_f32_16x16x32_bf16(pf, vf, oa[nt], 0, 0, 0);
    }

    #pragma unroll
    for (int nt = 0; nt < 8; ++nt)
        #pragma unroll
        for (int r = 0; r < 4; ++r) {
            const int m = quad * 4 + r;
            o[(size_t)(r0 + w * 16 + m) * DIM + h * HDIM + nt * 16 + col] =
                f2b(oa[nt][r] * inv[r]);
        }
}

// ---------------- launch ----------------
extern "C" void kernel_launch(void* const* d_in, const int* in_sizes, int n_in,
                              void* d_out, int out_size, void* d_ws, size_t ws_size,
                              hipStream_t stream)
{
    const float* x  = (const float*)d_in[0];
    const float* wq = (const float*)d_in[1];
    const float* wk = (const float*)d_in[2];
    const float* wv = (const float*)d_in[3];
    const float* wo = (const float*)d_in[4];
    const float* qw = (const float*)d_in[5];
    const float* kw = (const float*)d_in[6];
    float* out = (float*)d_out;

    // ws: xb 16MB | weights 8MB | xqkv 48MB | ob 16MB | inv 64KB  (~88MB)
    unsigned short* xb   = (unsigned short*)d_ws;
    unsigned short* wb   = xb + (size_t)MROWS * DIM;              // wq|wk|wv|wo
    unsigned short* xqkv = wb + (size_t)4 * DIM * DIM;
    unsigned short* ob   = xqkv + (size_t)MROWS * QKVDIM;
    float*          inv  = (float*)(ob + (size_t)MROWS * DIM);    // [2][MROWS]
    unsigned short* wob  = wb + (size_t)3 * DIM * DIM;

    cast_all<<<12288, 256, 0, stream>>>(x, wq, wk, wv, wo, xb, wb);

    gemm_nt_mfma<unsigned short><<<dim3(QKVDIM / 128, MROWS / 128), 256, 0, stream>>>(
        xb, wb, xqkv, MROWS, QKVDIM, DIM);

    rms_inv<<<MROWS, 256, 0, stream>>>(xqkv, inv);

    attn_mfma<<<dim3(MROWS / 64, NHEADS), 256, 0, stream>>>(xqkv, inv, qw, kw, ob);

    gemm_nt_mfma<float><<<dim3(DIM / 128, MROWS / 128), 256, 0, stream>>>(
        ob, wob, out, MROWS, DIM, DIM);
}